// Round 15
// baseline (561.728 us; speedup 1.0000x reference)
//
#include <hip/hip_runtime.h>
#include <hip/hip_bf16.h>
#include <math.h>

#define NN 16000
#define NPAD 16128
#define NE 256000
#define H 192
#define RP 256           // padded etab row: 64 lanes * 4 floats
#define NL 4
#define NBATCH 8
#define VEt 8
#define HH (H*H)

typedef __hip_bfloat16 bf16;
typedef unsigned short u16;
typedef unsigned char u8;
typedef unsigned int u32;
typedef __attribute__((ext_vector_type(8))) short bfrag_t;
typedef __attribute__((ext_vector_type(4))) float facc_t;
typedef __attribute__((ext_vector_type(4))) float f4;
typedef __attribute__((ext_vector_type(2))) unsigned uv2;

__device__ __forceinline__ bf16 f2b(float v){ return __float2bfloat16(v); }
__device__ __forceinline__ short f2bs(float v){ bf16 b = __float2bfloat16(v); return *(short*)&b; }

// ---- fp8 e4m3fn software encode, RTNE (fallback) ----
__device__ __forceinline__ unsigned enc8sw(float x){
    unsigned u = __float_as_uint(x);
    unsigned s = (u >> 24) & 0x80u;
    float ax = fabsf(x);
    if(ax >= 448.f) return s | 0x7Eu;
    if(ax < 0.015625f){
        int q = (int)rintf(ax * 512.f);
        return s | (unsigned)q;
    }
    unsigned au = u & 0x7FFFFFFFu;
    unsigned lsb = (au >> 20) & 1u;
    au += 0x7FFFFu + lsb;
    unsigned E = (au >> 23) - 127u;
    unsigned M = (au >> 20) & 7u;
    if((int)E > 8) return s | 0x7Eu;
    return s | ((E + 7u) << 3) | M;
}
__device__ __forceinline__ unsigned enc8(float x){
#if __has_builtin(__builtin_amdgcn_cvt_pk_fp8_f32)
    return (u32)__builtin_amdgcn_cvt_pk_fp8_f32(x, x, 0, false) & 0xFFu;
#else
    return enc8sw(x);
#endif
}
template<int SEL>
__device__ __forceinline__ float dec8s(u32 w){
#if __has_builtin(__builtin_amdgcn_cvt_f32_fp8)
    return __builtin_amdgcn_cvt_f32_fp8((int)w, SEL);
#else
    unsigned v = (w >> (SEL*8)) & 0xFFu;
    unsigned e = (v >> 3) & 15u, m = v & 7u;
    float mag = e ? __builtin_ldexpf((float)(8u + m), (int)e - 10)
                  : __builtin_ldexpf((float)m, -9);
    return (v & 0x80u) ? -mag : mag;
#endif
}
__device__ __forceinline__ float frcp(float x){
#if __has_builtin(__builtin_amdgcn_rcpf)
    return __builtin_amdgcn_rcpf(x);
#else
    return 1.f/x;
#endif
}
__device__ __forceinline__ float fsilu(float v){ return v*frcp(1.f + __expf(-v)); }

__global__ void k_sentinel(float* __restrict__ out, float v){ out[0] = v; }

// ---------------- transpose 18 H×H fp32 weight mats into bf16 [n][k] ----------------
__global__ void k_transpose(const float* __restrict__ wq, const float* __restrict__ wk,
                            const float* __restrict__ wv, const float* __restrict__ wsk,
                            const float* __restrict__ w1, u16* __restrict__ wt){
    int mat = blockIdx.x;
    const float* src;
    if(mat < 4)       src = wq  + (size_t)mat*HH;
    else if(mat < 8)  src = wk  + (size_t)(mat-4)*HH;
    else if(mat < 12) src = wv  + (size_t)(mat-8)*HH;
    else if(mat < 16) src = wsk + (size_t)(mat-12)*HH;
    else              src = w1  + (size_t)(mat-16)*HH;
    u16* dst = wt + (size_t)mat*HH;
    const int slice = HH/8;
    int base = blockIdx.y*slice;
    for(int i = base + threadIdx.x; i < base + slice; i += blockDim.x){
        int k = i / H, n = i % H;
        bf16 b = f2b(src[i]);
        dst[n*H + k] = *(u16*)&b;
    }
}

// ---------------- W2^T bf16 [16][192] (rows >=8 zero) ----------------
__global__ void k_w2t(const float* __restrict__ w2, u16* __restrict__ w2t){
    for(int i = threadIdx.x; i < 16*H; i += blockDim.x){
        int n = i / H, k = i % H;
        bf16 b = f2b(n < 8 ? w2[k*8 + n] : 0.f);
        w2t[i] = *(u16*)&b;
    }
}

// ---------------- time embedding MLP ----------------
__global__ void k_tvec(const int* __restrict__ tg, const float* __restrict__ w1,
                       const float* __restrict__ b1, const float* __restrict__ w2,
                       const float* __restrict__ b2, float* __restrict__ tvec){
    int b = blockIdx.x, j = threadIdx.x;
    __shared__ float emb[H], h1[H];
    float t = (float)tg[b];
    if(j < 96){
        float fr = __expf(-logf(10000.0f) * (float)j / 96.0f);
        float ang = t * fr;
        emb[j]      = sinf(ang);
        emb[j + 96] = cosf(ang);
    }
    __syncthreads();
    float acc = b1[j];
    for(int k = 0; k < H; k++) acc += emb[k] * w1[k*H + j];
    h1[j] = acc / (1.f + __expf(-acc));
    __syncthreads();
    float acc2 = b2[j];
    for(int k = 0; k < H; k++) acc2 += h1[k] * w2[k*H + j];
    tvec[b*H + j] = acc2;
}

// ---------------- x0 ----------------
__global__ void k_init_x(const float* __restrict__ nemb, const float* __restrict__ memb,
                         const float* __restrict__ tvec, const int* __restrict__ ntype,
                         const int* __restrict__ emask, const int* __restrict__ nbatch,
                         float* __restrict__ x, u16* __restrict__ xb){
    int idx = blockIdx.x*blockDim.x + threadIdx.x;
    if(idx >= NN*H) return;
    int n = idx / H, c = idx % H;
    float v = nemb[(size_t)ntype[n]*H + c] + tvec[nbatch[n]*H + c]
            + memb[(size_t)emask[n]*H + c];
    x[idx] = v;
    bf16 b = f2b(v); xb[idx] = *(u16*)&b;
}

// ---------------- counting sort ----------------
__global__ void k_zero_i(int* __restrict__ p, int n){
    int i = blockIdx.x*blockDim.x + threadIdx.x;
    if(i < n) p[i] = 0;
}
__global__ void k_count(const int* __restrict__ edst, int* __restrict__ cnt){
    int e = blockIdx.x*blockDim.x + threadIdx.x;
    if(e < NE) atomicAdd(&cnt[edst[e]], 1);
}
__global__ __launch_bounds__(1024) void k_scan(const int* __restrict__ cnt,
                                               int* __restrict__ ofs, int* __restrict__ cur){
    __shared__ int wsum[16];
    __shared__ int carry_s;
    int tid = threadIdx.x, lane = tid & 63, w = tid >> 6;
    if(tid == 0) carry_s = 0;
    __syncthreads();
    for(int base = 0; base < NN; base += 1024){
        int idx = base + tid;
        int v = (idx < NN) ? cnt[idx] : 0;
        int sc = v;
        #pragma unroll
        for(int o = 1; o < 64; o <<= 1){
            int t = __shfl_up(sc, o);
            if(lane >= o) sc += t;
        }
        if(lane == 63) wsum[w] = sc;
        __syncthreads();
        if(w == 0){
            int ws = (lane < 16) ? wsum[lane] : 0;
            #pragma unroll
            for(int o = 1; o < 16; o <<= 1){
                int t = __shfl_up(ws, o);
                if(lane >= o) ws += t;
            }
            if(lane < 16) wsum[lane] = ws;
        }
        __syncthreads();
        int wbase = (w > 0) ? wsum[w-1] : 0;
        int c = carry_s;
        int excl = c + wbase + sc - v;
        if(idx < NN){ ofs[idx] = excl; cur[idx] = excl; }
        __syncthreads();
        if(tid == 0) carry_s = c + wsum[15];
        __syncthreads();
    }
    if(threadIdx.x == 0) ofs[NN] = carry_s;
}
__global__ void k_scatter(const int* __restrict__ esrc, const int* __restrict__ edst,
                          const int* __restrict__ etype, const int* __restrict__ nbatch,
                          int* __restrict__ cur, int* __restrict__ ssrc, int* __restrict__ seix){
    int e = blockIdx.x*blockDim.x + threadIdx.x;
    if(e >= NE) return;
    int s = esrc[e], d = edst[e];
    int pos = atomicAdd(&cur[d], 1);
    ssrc[pos] = s;
    seix[pos] = nbatch[s]*VEt + etype[e];
}

// ---------------- e-tables (padded rows: RP floats) ----------------
__global__ void k_etab(const float* __restrict__ eemb, const float* __restrict__ tvec,
                       const float* __restrict__ we, float* __restrict__ etab){
    int blk = blockIdx.x;
    int l = blk >> 6, idx = blk & 63, b = idx >> 3, et = idx & 7;
    int c = threadIdx.x;
    __shared__ float a[H];
    a[c] = eemb[et*H + c] + tvec[b*H + c];
    __syncthreads();
    float acc = 0.f;
    const float* w = we + (size_t)l*HH;
    for(int k = 0; k < H; k++) acc += a[k] * w[k*H + c];
    etab[(size_t)blk*RP + (c/3)*4 + (c%3)] = acc;
}

// ---------------- c-table (dense 192 floats) ----------------
__global__ void k_ctab(const float* __restrict__ eemb, const float* __restrict__ tvec,
                       const float* __restrict__ w1, const float* __restrict__ b1,
                       float* __restrict__ ctab){
    int idx = blockIdx.x, b = idx >> 3, et = idx & 7;
    int c = threadIdx.x;
    __shared__ float a[H];
    a[c] = eemb[et*H + c] + tvec[b*H + c];
    __syncthreads();
    float acc = b1[c];
    for(int k = 0; k < H; k++){
        acc += a[k]          * w1[(size_t)(2*H + k)*H + c];
        acc += tvec[b*H + k] * w1[(size_t)(3*H + k)*H + c];
    }
    ctab[(size_t)idx*H + c] = acc;
}

// ---------------- MFMA GEMM; obf: 0=fp32 dense-H, 2=fp8 KV word0, 3=fp8 KV word1, 4=fp8 dense-192 ----------------
struct GemmP {
    const u16* wt[4];
    const float* bias[4];
    void* out[4];
    int obf[4];
};
__global__ __launch_bounds__(256) void k_gemm(const u16* __restrict__ A, GemmP P){
    int oi = blockIdx.y / 3, nt = blockIdx.y % 3;
    const u16* Wt = P.wt[oi];
    const float* bias = P.bias[oi];
    int wave = threadIdx.x >> 6, lane = threadIdx.x & 63;
    int quad = lane >> 4, l16 = lane & 15;
    int m0 = blockIdx.x*256 + wave*64;
    int n0 = nt*64;
    facc_t acc[4][4];
    #pragma unroll
    for(int i = 0; i < 4; i++)
        #pragma unroll
        for(int j = 0; j < 4; j++){ acc[i][j][0]=0.f; acc[i][j][1]=0.f; acc[i][j][2]=0.f; acc[i][j][3]=0.f; }
    #pragma unroll
    for(int kc = 0; kc < 6; kc++){
        int kb = kc*32 + quad*8;
        bfrag_t af[4], bg[4];
        #pragma unroll
        for(int i = 0; i < 4; i++) af[i] = *(const bfrag_t*)(A  + (size_t)(m0 + i*16 + l16)*H + kb);
        #pragma unroll
        for(int j = 0; j < 4; j++) bg[j] = *(const bfrag_t*)(Wt + (size_t)(n0 + j*16 + l16)*H + kb);
        #pragma unroll
        for(int i = 0; i < 4; i++)
            #pragma unroll
            for(int j = 0; j < 4; j++)
                acc[i][j] = __builtin_amdgcn_mfma_f32_16x16x32_bf16(af[i], bg[j], acc[i][j], 0, 0, 0);
    }
    float bv[4];
    #pragma unroll
    for(int j = 0; j < 4; j++) bv[j] = bias ? bias[n0 + j*16 + l16] : 0.f;
    int code = P.obf[oi];
    if(code == 0){
        float* out = (float*)P.out[oi];
        #pragma unroll
        for(int i = 0; i < 4; i++){
            int rb = m0 + i*16 + quad*4;
            #pragma unroll
            for(int r = 0; r < 4; r++){
                int row = rb + r;
                if(row < NN){
                    #pragma unroll
                    for(int j = 0; j < 4; j++)
                        out[(size_t)row*H + n0 + j*16 + l16] = acc[i][j][r] + bv[j];
                }
            }
        }
    } else {
        u8* out = (u8*)P.out[oi];
        int rstride = (code == 4) ? 192 : 512;
        int byteoff[4];
        #pragma unroll
        for(int j = 0; j < 4; j++){
            int c = n0 + j*16 + l16;
            if(code == 4)      byteoff[j] = c;
            else if(code == 2) byteoff[j] = (c/3)*8 + (c%3);
            else               byteoff[j] = (c/3)*8 + 4 + (c%3);
        }
        #pragma unroll
        for(int i = 0; i < 4; i++){
            int rb = m0 + i*16 + quad*4;
            #pragma unroll
            for(int r = 0; r < 4; r++){
                int row = rb + r;
                if(row < NN){
                    #pragma unroll
                    for(int j = 0; j < 4; j++)
                        out[(size_t)row*rstride + byteoff[j]] = (u8)enc8(acc[i][j][r] + bv[j]);
                }
            }
        }
    }
}

// ---------------- fused attention + gate + LN; no-max softmax, 4-stream, packed KV ----------------
__global__ __launch_bounds__(256) void k_attn(
    const float* __restrict__ Q, const u8* __restrict__ KV,
    const float* __restrict__ XR,
    const float* __restrict__ etab, const int* __restrict__ ofs,
    const int* __restrict__ ssrc, const int* __restrict__ seix,
    const float* __restrict__ wb, const float* __restrict__ lng, const float* __restrict__ lnb,
    float* __restrict__ x, u16* __restrict__ xb)
{
    int n = blockIdx.x*4 + (threadIdx.x >> 6);
    int lane = threadIdx.x & 63;
    int ch = lane*3;
    size_t base = (size_t)n*H + ch;
    const float scale = 0.14433756729740646f;   // 1/sqrt(48)
    float q0 = Q[base], q1 = Q[base+1], q2 = Q[base+2];
    int p0 = ofs[n], p1 = ofs[n+1];
    float lac[4]  = {0.f,0.f,0.f,0.f};
    float ac0[4]  = {0.f,0.f,0.f,0.f};
    float ac1[4]  = {0.f,0.f,0.f,0.f};
    float ac2[4]  = {0.f,0.f,0.f,0.f};
    int p = p0;
    for(; p + 3 < p1; p += 4){
        int s[4], ei[4];
        #pragma unroll
        for(int t = 0; t < 4; t++){ s[t] = ssrc[p+t]; ei[t] = seix[p+t]; }
        uv2 kv[4];
        f4 ef[4];
        #pragma unroll
        for(int t = 0; t < 4; t++){
            kv[t] = *(const uv2*)(KV + (size_t)s[t]*512 + lane*8);
            ef[t] = *(const f4*)(etab + (size_t)ei[t]*RP + lane*4);
        }
        float tt[4];
        #pragma unroll
        for(int t = 0; t < 4; t++)
            tt[t] = q0*(dec8s<0>(kv[t].x)+ef[t].x) + q1*(dec8s<1>(kv[t].x)+ef[t].y)
                  + q2*(dec8s<2>(kv[t].x)+ef[t].z);
        #pragma unroll
        for(int o = 1; o <= 8; o <<= 1){
            #pragma unroll
            for(int t = 0; t < 4; t++) tt[t] += __shfl_xor(tt[t], o);
        }
        #pragma unroll
        for(int t = 0; t < 4; t++){
            float sc = fminf(fmaxf(tt[t]*scale, -60.f), 60.f);
            float pw = __expf(sc);
            lac[t] += pw;
            ac0[t] += pw*(dec8s<0>(kv[t].y)+ef[t].x);
            ac1[t] += pw*(dec8s<1>(kv[t].y)+ef[t].y);
            ac2[t] += pw*(dec8s<2>(kv[t].y)+ef[t].z);
        }
    }
    for(; p < p1; p++){
        int sA = ssrc[p], eiA = seix[p];
        uv2 kv = *(const uv2*)(KV + (size_t)sA*512 + lane*8);
        f4 efA = *(const f4*)(etab + (size_t)eiA*RP + lane*4);
        float tA = q0*(dec8s<0>(kv.x)+efA.x) + q1*(dec8s<1>(kv.x)+efA.y) + q2*(dec8s<2>(kv.x)+efA.z);
        tA += __shfl_xor(tA,1); tA += __shfl_xor(tA,2); tA += __shfl_xor(tA,4); tA += __shfl_xor(tA,8);
        float sc = fminf(fmaxf(tA*scale, -60.f), 60.f);
        float pw = __expf(sc);
        lac[0] += pw;
        ac0[0] += pw*(dec8s<0>(kv.y)+efA.x);
        ac1[0] += pw*(dec8s<1>(kv.y)+efA.y);
        ac2[0] += pw*(dec8s<2>(kv.y)+efA.z);
    }
    float l  = (lac[0]+lac[1]) + (lac[2]+lac[3]);
    float a0 = (ac0[0]+ac0[1]) + (ac0[2]+ac0[3]);
    float a1 = (ac1[0]+ac1[1]) + (ac1[2]+ac1[3]);
    float a2 = (ac2[0]+ac2[1]) + (ac2[2]+ac2[3]);
    float inv = (p1 > p0) ? 1.f/l : 0.f;
    float o0 = a0*inv, o1 = a1*inv, o2 = a2*inv;
    float xr0 = XR[base], xr1 = XR[base+1], xr2 = XR[base+2];
    float sd = o0*wb[ch]  + o1*wb[ch+1]  + o2*wb[ch+2]
             + xr0*wb[H+ch] + xr1*wb[H+ch+1] + xr2*wb[H+ch+2]
             + (o0-xr0)*wb[2*H+ch] + (o1-xr1)*wb[2*H+ch+1] + (o2-xr2)*wb[2*H+ch+2];
    sd += __shfl_xor(sd,1); sd += __shfl_xor(sd,2); sd += __shfl_xor(sd,4);
    sd += __shfl_xor(sd,8); sd += __shfl_xor(sd,16); sd += __shfl_xor(sd,32);
    float beta = 1.f/(1.f + __expf(-sd));
    float h0 = beta*xr0 + (1.f-beta)*o0;
    float h1 = beta*xr1 + (1.f-beta)*o1;
    float h2 = beta*xr2 + (1.f-beta)*o2;
    float y0 = x[base] + h0, y1 = x[base+1] + h1, y2 = x[base+2] + h2;
    float s3 = y0 + y1 + y2;
    s3 += __shfl_xor(s3,1); s3 += __shfl_xor(s3,2); s3 += __shfl_xor(s3,4);
    s3 += __shfl_xor(s3,8); s3 += __shfl_xor(s3,16); s3 += __shfl_xor(s3,32);
    float mean = s3 * (1.f/H);
    float d0 = y0-mean, d1 = y1-mean, d2 = y2-mean;
    float v3 = d0*d0 + d1*d1 + d2*d2;
    v3 += __shfl_xor(v3,1); v3 += __shfl_xor(v3,2); v3 += __shfl_xor(v3,4);
    v3 += __shfl_xor(v3,8); v3 += __shfl_xor(v3,16); v3 += __shfl_xor(v3,32);
    float rs = rsqrtf(v3*(1.f/H) + 1e-5f);
    float z0 = d0*rs*lng[ch]   + lnb[ch];
    float z1 = d1*rs*lng[ch+1] + lnb[ch+1];
    float z2 = d2*rs*lng[ch+2] + lnb[ch+2];
    x[base] = z0; x[base+1] = z1; x[base+2] = z2;
    bf16 t0 = f2b(z0), t1 = f2b(z1), t2 = f2b(z2);
    xb[base] = *(u16*)&t0; xb[base+1] = *(u16*)&t1; xb[base+2] = *(u16*)&t2;
}

// ---------------- node logits ----------------
__global__ void k_nodeout(const float* __restrict__ x, const float* __restrict__ w,
                          const float* __restrict__ b, float* __restrict__ out){
    int j = threadIdx.x & 31;
    int n = blockIdx.x*8 + (threadIdx.x >> 5);
    float acc = b[j];
    const float* xr = x + (size_t)n*H;
    for(int k = 0; k < H; k++) acc += xr[k] * w[k*32 + j];
    out[(size_t)n*32 + j] = acc;
}

// ---------------- edge logits: MFMA over 16 edges/wave ----------------
__global__ __launch_bounds__(256) void k_edgemlp(
    const int* __restrict__ esrc, const int* __restrict__ edst, const int* __restrict__ etype,
    const int* __restrict__ nb,
    const u8* __restrict__ xs1, const u8* __restrict__ xd1, const float* __restrict__ ctab,
    const u16* __restrict__ w2t, const float* __restrict__ b2p, float* __restrict__ out)
{
    int wid = blockIdx.x*4 + (threadIdx.x >> 6);
    int lane = threadIdx.x & 63;
    int l16 = lane & 15, quad = lane >> 4;
    int e0 = wid*16;
    int e = e0 + l16;
    int s = esrc[e], d = edst[e];
    int ct = nb[s]*VEt + etype[e];
    const u8* ap = xs1 + (size_t)s*192;
    const u8* bp = xd1 + (size_t)d*192;
    const float* cp = ctab + (size_t)ct*H;
    facc_t acc = {0.f, 0.f, 0.f, 0.f};
    #pragma unroll
    for(int kc = 0; kc < 6; kc++){
        int kb = quad*8 + kc*32;
        u32 aw0 = *(const u32*)(ap + kb), aw1 = *(const u32*)(ap + kb + 4);
        u32 bw0 = *(const u32*)(bp + kb), bw1 = *(const u32*)(bp + kb + 4);
        f4 c0 = *(const f4*)(cp + kb);
        f4 c1 = *(const f4*)(cp + kb + 4);
        float h0 = fsilu(dec8s<0>(aw0) + dec8s<0>(bw0) + c0.x);
        float h1 = fsilu(dec8s<1>(aw0) + dec8s<1>(bw0) + c0.y);
        float h2 = fsilu(dec8s<2>(aw0) + dec8s<2>(bw0) + c0.z);
        float h3 = fsilu(dec8s<3>(aw0) + dec8s<3>(bw0) + c0.w);
        float h4 = fsilu(dec8s<0>(aw1) + dec8s<0>(bw1) + c1.x);
        float h5 = fsilu(dec8s<1>(aw1) + dec8s<1>(bw1) + c1.y);
        float h6 = fsilu(dec8s<2>(aw1) + dec8s<2>(bw1) + c1.z);
        float h7 = fsilu(dec8s<3>(aw1) + dec8s<3>(bw1) + c1.w);
        bfrag_t af;
        af[0] = f2bs(h0); af[1] = f2bs(h1); af[2] = f2bs(h2); af[3] = f2bs(h3);
        af[4] = f2bs(h4); af[5] = f2bs(h5); af[6] = f2bs(h6); af[7] = f2bs(h7);
        bfrag_t wf = *(const bfrag_t*)(w2t + (size_t)l16*H + kb);
        acc = __builtin_amdgcn_mfma_f32_16x16x32_bf16(af, wf, acc, 0, 0, 0);
    }
    if(l16 < 8){
        float bo = b2p[l16];
        #pragma unroll
        for(int r = 0; r < 4; r++){
            int eo = e0 + quad*4 + r;
            out[(size_t)eo*8 + l16] = acc[r] + bo;
        }
    }
}

extern "C" void kernel_launch(void* const* d_in, const int* in_sizes, int n_in,
                              void* d_out, int out_size, void* d_ws, size_t ws_size,
                              hipStream_t stream)
{
    {
        int bad = -1;
        if(n_in != 31) bad = 100;
        else {
            const int chk_idx[9] = {0, 7, 16, 21, 23, 26, 27, 29, 30};
            const int chk_sz [9] = {32*H, NL*HH, NL*3*H, 4*HH, H*8, NE, 2*NE, NN, NBATCH};
            for(int i = 0; i < 9; i++) if(in_sizes[chk_idx[i]] != chk_sz[i]){ bad = chk_idx[i]; break; }
        }
        if(bad >= 0){ k_sentinel<<<1,1,0,stream>>>((float*)d_out, 20000.f + 256.f*bad); return; }
        if(out_size != NN*32 + NE*8){ k_sentinel<<<1,1,0,stream>>>((float*)d_out, 30000.f); return; }
    }

    const float* node_emb = (const float*)d_in[0];
    const float* edge_emb = (const float*)d_in[1];
    const float* time_w1  = (const float*)d_in[2];
    const float* time_b1  = (const float*)d_in[3];
    const float* time_w2  = (const float*)d_in[4];
    const float* time_b2  = (const float*)d_in[5];
    const float* mask_emb = (const float*)d_in[6];
    const float* wq       = (const float*)d_in[7];
    const float* bq       = (const float*)d_in[8];
    const float* wk       = (const float*)d_in[9];
    const float* bk       = (const float*)d_in[10];
    const float* wv       = (const float*)d_in[11];
    const float* bv       = (const float*)d_in[12];
    const float* we       = (const float*)d_in[13];
    const float* wskip    = (const float*)d_in[14];
    const float* bskip    = (const float*)d_in[15];
    const float* wbeta    = (const float*)d_in[16];
    const float* ln_g     = (const float*)d_in[17];
    const float* ln_b     = (const float*)d_in[18];
    const float* now      = (const float*)d_in[19];
    const float* nob      = (const float*)d_in[20];
    const float* ew1      = (const float*)d_in[21];
    const float* eb1      = (const float*)d_in[22];
    const float* ew2      = (const float*)d_in[23];
    const float* eb2      = (const float*)d_in[24];
    const int* node_type  = (const int*)d_in[25];
    const int* edge_type  = (const int*)d_in[26];
    const int* edge_index = (const int*)d_in[27];
    const int* edit_mask  = (const int*)d_in[28];
    const int* node_batch = (const int*)d_in[29];
    const int* t_graph    = (const int*)d_in[30];
    const int* esrc = edge_index;
    const int* edst = edge_index + NE;

    char* wsb = (char*)d_ws;
    size_t off = 0;
    auto take = [&](size_t bytes) -> char* {
        char* r = wsb + off;
        off += (bytes + 255) & ~(size_t)255;
        return r;
    };
    float* tvec = (float*)take((size_t)NBATCH*H*4);
    float* x    = (float*)take((size_t)NN*H*4);
    u16*   xb   = (u16*)  take((size_t)NPAD*H*2);
    float* Q    = (float*)take((size_t)NN*H*4);
    u8*    KV   = (u8*)   take((size_t)NN*512);
    float* XR   = (float*)take((size_t)NN*H*4);
    u8*    xs1  = (u8*)   take((size_t)NN*192);
    u8*    xd1  = (u8*)   take((size_t)NN*192);
    float* etab = (float*)take((size_t)NL*64*RP*4);
    float* ctab = (float*)take((size_t)64*H*4);
    u16*   wt   = (u16*)  take((size_t)18*HH*2);
    u16*   w2t  = (u16*)  take((size_t)16*H*2);
    int* cnt    = (int*)  take((size_t)(NN+1)*4);
    int* offa   = (int*)  take((size_t)(NN+1)*4);
    int* cur    = (int*)  take((size_t)(NN+1)*4);
    int* ssrc   = (int*)  take((size_t)NE*4);
    int* seix   = (int*)  take((size_t)NE*4);

    if(ws_size < off){
        k_sentinel<<<1,1,0,stream>>>((float*)d_out, 10000.f + (float)(ws_size >> 20));
        return;
    }

    k_transpose<<<dim3(18, 8), 256, 0, stream>>>(wq, wk, wv, wskip, ew1, wt);
    k_w2t<<<1, 256, 0, stream>>>(ew2, w2t);
    k_tvec<<<NBATCH, H, 0, stream>>>(t_graph, time_w1, time_b1, time_w2, time_b2, tvec);
    k_init_x<<<(NN*H + 255)/256, 256, 0, stream>>>(node_emb, mask_emb, tvec, node_type,
                                                   edit_mask, node_batch, x, xb);
    k_zero_i<<<(NN + 255)/256, 256, 0, stream>>>(cnt, NN);
    k_count<<<NE/256, 256, 0, stream>>>(edst, cnt);
    k_scan<<<1, 1024, 0, stream>>>(cnt, offa, cur);
    k_scatter<<<NE/256, 256, 0, stream>>>(esrc, edst, edge_type, node_batch, cur, ssrc, seix);
    k_etab<<<NL*64, H, 0, stream>>>(edge_emb, tvec, we, etab);
    k_ctab<<<64, H, 0, stream>>>(edge_emb, tvec, ew1, eb1, ctab);

    for(int l = 0; l < NL; l++){
        GemmP P;
        P.wt[0] = wt + (size_t)(0  + l)*HH;  P.bias[0] = bq   + (size_t)l*H;  P.out[0] = Q;  P.obf[0] = 0;
        P.wt[1] = wt + (size_t)(4  + l)*HH;  P.bias[1] = bk   + (size_t)l*H;  P.out[1] = KV; P.obf[1] = 2;
        P.wt[2] = wt + (size_t)(8  + l)*HH;  P.bias[2] = bv   + (size_t)l*H;  P.out[2] = KV; P.obf[2] = 3;
        P.wt[3] = wt + (size_t)(12 + l)*HH;  P.bias[3] = bskip+ (size_t)l*H;  P.out[3] = XR; P.obf[3] = 0;
        k_gemm<<<dim3(63, 12), 256, 0, stream>>>(xb, P);
        k_attn<<<NN/4, 256, 0, stream>>>(Q, KV, XR, etab + (size_t)l*64*RP, offa, ssrc, seix,
                                         wbeta + (size_t)l*3*H, ln_g + (size_t)l*H,
                                         ln_b + (size_t)l*H, x, xb);
    }
    {
        GemmP P;
        P.wt[0] = wt + (size_t)16*HH; P.bias[0] = nullptr; P.out[0] = xs1; P.obf[0] = 4;
        P.wt[1] = wt + (size_t)17*HH; P.bias[1] = nullptr; P.out[1] = xd1; P.obf[1] = 4;
        P.wt[2] = P.wt[0]; P.bias[2] = nullptr; P.out[2] = xs1; P.obf[2] = 4;
        P.wt[3] = P.wt[0]; P.bias[3] = nullptr; P.out[3] = xs1; P.obf[3] = 4;
        k_gemm<<<dim3(63, 6), 256, 0, stream>>>(xb, P);
    }
    k_nodeout<<<NN/8, 256, 0, stream>>>(x, now, nob, (float*)d_out);
    k_edgemlp<<<NE/64, 256, 0, stream>>>(esrc, edst, edge_type, node_batch, xs1, xd1, ctab,
                                         w2t, eb2, (float*)d_out + (size_t)NN*32);
}

// Round 16
// 560.435 us; speedup vs baseline: 1.0023x; 1.0023x over previous
//
#include <hip/hip_runtime.h>
#include <hip/hip_bf16.h>
#include <math.h>

#define NN 16000
#define NPAD 16128
#define NE 256000
#define H 192
#define RP 256           // padded row: 64 lanes * 4 (bytes for fp8, floats for tables)
#define NL 4
#define NBATCH 8
#define VEt 8
#define HH (H*H)
#define EML 16

typedef __hip_bfloat16 bf16;
typedef unsigned short u16;
typedef unsigned char u8;
typedef unsigned int u32;
typedef __attribute__((ext_vector_type(8))) short bfrag_t;
typedef __attribute__((ext_vector_type(4))) float facc_t;
typedef __attribute__((ext_vector_type(4))) float f4;

__device__ __forceinline__ bf16 f2b(float v){ return __float2bfloat16(v); }

// ---- fp8 e4m3fn software encode, RTNE (fallback) ----
__device__ __forceinline__ unsigned enc8sw(float x){
    unsigned u = __float_as_uint(x);
    unsigned s = (u >> 24) & 0x80u;
    float ax = fabsf(x);
    if(ax >= 448.f) return s | 0x7Eu;
    if(ax < 0.015625f){
        int q = (int)rintf(ax * 512.f);
        return s | (unsigned)q;
    }
    unsigned au = u & 0x7FFFFFFFu;
    unsigned lsb = (au >> 20) & 1u;
    au += 0x7FFFFu + lsb;
    unsigned E = (au >> 23) - 127u;
    unsigned M = (au >> 20) & 7u;
    if((int)E > 8) return s | 0x7Eu;
    return s | ((E + 7u) << 3) | M;
}
__device__ __forceinline__ unsigned enc8(float x){
#if __has_builtin(__builtin_amdgcn_cvt_pk_fp8_f32)
    return (u32)__builtin_amdgcn_cvt_pk_fp8_f32(x, x, 0, false) & 0xFFu;
#else
    return enc8sw(x);
#endif
}
template<int SEL>
__device__ __forceinline__ float dec8s(u32 w){
#if __has_builtin(__builtin_amdgcn_cvt_f32_fp8)
    return __builtin_amdgcn_cvt_f32_fp8((int)w, SEL);
#else
    unsigned v = (w >> (SEL*8)) & 0xFFu;
    unsigned e = (v >> 3) & 15u, m = v & 7u;
    float mag = e ? __builtin_ldexpf((float)(8u + m), (int)e - 10)
                  : __builtin_ldexpf((float)m, -9);
    return (v & 0x80u) ? -mag : mag;
#endif
}
__device__ __forceinline__ float frcp(float x){
#if __has_builtin(__builtin_amdgcn_rcpf)
    return __builtin_amdgcn_rcpf(x);
#else
    return 1.f/x;
#endif
}

__global__ void k_sentinel(float* __restrict__ out, float v){ out[0] = v; }

// ---------------- transpose 18 H×H fp32 weight mats into bf16 [n][k] ----------------
__global__ void k_transpose(const float* __restrict__ wq, const float* __restrict__ wk,
                            const float* __restrict__ wv, const float* __restrict__ wsk,
                            const float* __restrict__ w1, u16* __restrict__ wt){
    int mat = blockIdx.x;
    const float* src;
    if(mat < 4)       src = wq  + (size_t)mat*HH;
    else if(mat < 8)  src = wk  + (size_t)(mat-4)*HH;
    else if(mat < 12) src = wv  + (size_t)(mat-8)*HH;
    else if(mat < 16) src = wsk + (size_t)(mat-12)*HH;
    else              src = w1  + (size_t)(mat-16)*HH;
    u16* dst = wt + (size_t)mat*HH;
    const int slice = HH/8;
    int base = blockIdx.y*slice;
    for(int i = base + threadIdx.x; i < base + slice; i += blockDim.x){
        int k = i / H, n = i % H;
        bf16 b = f2b(src[i]);
        dst[n*H + k] = *(u16*)&b;
    }
}

// ---------------- time embedding MLP ----------------
__global__ void k_tvec(const int* __restrict__ tg, const float* __restrict__ w1,
                       const float* __restrict__ b1, const float* __restrict__ w2,
                       const float* __restrict__ b2, float* __restrict__ tvec){
    int b = blockIdx.x, j = threadIdx.x;
    __shared__ float emb[H], h1[H];
    float t = (float)tg[b];
    if(j < 96){
        float fr = __expf(-logf(10000.0f) * (float)j / 96.0f);
        float ang = t * fr;
        emb[j]      = sinf(ang);
        emb[j + 96] = cosf(ang);
    }
    __syncthreads();
    float acc = b1[j];
    for(int k = 0; k < H; k++) acc += emb[k] * w1[k*H + j];
    h1[j] = acc / (1.f + __expf(-acc));
    __syncthreads();
    float acc2 = b2[j];
    for(int k = 0; k < H; k++) acc2 += h1[k] * w2[k*H + j];
    tvec[b*H + j] = acc2;
}

// ---------------- x0 ----------------
__global__ void k_init_x(const float* __restrict__ nemb, const float* __restrict__ memb,
                         const float* __restrict__ tvec, const int* __restrict__ ntype,
                         const int* __restrict__ emask, const int* __restrict__ nbatch,
                         float* __restrict__ x, u16* __restrict__ xb){
    int idx = blockIdx.x*blockDim.x + threadIdx.x;
    if(idx >= NN*H) return;
    int n = idx / H, c = idx % H;
    float v = nemb[(size_t)ntype[n]*H + c] + tvec[nbatch[n]*H + c]
            + memb[(size_t)emask[n]*H + c];
    x[idx] = v;
    bf16 b = f2b(v); xb[idx] = *(u16*)&b;
}

// ---------------- counting sort ----------------
__global__ void k_zero_i(int* __restrict__ p, int n){
    int i = blockIdx.x*blockDim.x + threadIdx.x;
    if(i < n) p[i] = 0;
}
__global__ void k_count(const int* __restrict__ edst, int* __restrict__ cnt){
    int e = blockIdx.x*blockDim.x + threadIdx.x;
    if(e < NE) atomicAdd(&cnt[edst[e]], 1);
}
__global__ __launch_bounds__(1024) void k_scan(const int* __restrict__ cnt,
                                               int* __restrict__ ofs, int* __restrict__ cur){
    __shared__ int wsum[16];
    __shared__ int carry_s;
    int tid = threadIdx.x, lane = tid & 63, w = tid >> 6;
    if(tid == 0) carry_s = 0;
    __syncthreads();
    for(int base = 0; base < NN; base += 1024){
        int idx = base + tid;
        int v = (idx < NN) ? cnt[idx] : 0;
        int sc = v;
        #pragma unroll
        for(int o = 1; o < 64; o <<= 1){
            int t = __shfl_up(sc, o);
            if(lane >= o) sc += t;
        }
        if(lane == 63) wsum[w] = sc;
        __syncthreads();
        if(w == 0){
            int ws = (lane < 16) ? wsum[lane] : 0;
            #pragma unroll
            for(int o = 1; o < 16; o <<= 1){
                int t = __shfl_up(ws, o);
                if(lane >= o) ws += t;
            }
            if(lane < 16) wsum[lane] = ws;
        }
        __syncthreads();
        int wbase = (w > 0) ? wsum[w-1] : 0;
        int c = carry_s;
        int excl = c + wbase + sc - v;
        if(idx < NN){ ofs[idx] = excl; cur[idx] = excl; }
        __syncthreads();
        if(tid == 0) carry_s = c + wsum[15];
        __syncthreads();
    }
    if(threadIdx.x == 0) ofs[NN] = carry_s;
}
__global__ void k_scatter(const int* __restrict__ esrc, const int* __restrict__ edst,
                          const int* __restrict__ etype, const int* __restrict__ nbatch,
                          int* __restrict__ cur, int* __restrict__ ssrc, int* __restrict__ seix,
                          int* __restrict__ sdst, int* __restrict__ seorig){
    int e = blockIdx.x*blockDim.x + threadIdx.x;
    if(e >= NE) return;
    int s = esrc[e], d = edst[e];
    int pos = atomicAdd(&cur[d], 1);
    ssrc[pos] = s;
    seix[pos] = nbatch[s]*VEt + etype[e];
    sdst[pos] = d;
    seorig[pos] = e;
}

// ---------------- e-tables (padded rows: RP floats, lane*4 + t) ----------------
__global__ void k_etab(const float* __restrict__ eemb, const float* __restrict__ tvec,
                       const float* __restrict__ we, float* __restrict__ etab){
    int blk = blockIdx.x;
    int l = blk >> 6, idx = blk & 63, b = idx >> 3, et = idx & 7;
    int c = threadIdx.x;
    __shared__ float a[H];
    a[c] = eemb[et*H + c] + tvec[b*H + c];
    __syncthreads();
    float acc = 0.f;
    const float* w = we + (size_t)l*HH;
    for(int k = 0; k < H; k++) acc += a[k] * w[k*H + c];
    etab[(size_t)blk*RP + (c/3)*4 + (c%3)] = acc;
}

// ---------------- c-table (padded) ----------------
__global__ void k_ctab(const float* __restrict__ eemb, const float* __restrict__ tvec,
                       const float* __restrict__ w1, const float* __restrict__ b1,
                       float* __restrict__ ctab){
    int idx = blockIdx.x, b = idx >> 3, et = idx & 7;
    int c = threadIdx.x;
    __shared__ float a[H];
    a[c] = eemb[et*H + c] + tvec[b*H + c];
    __syncthreads();
    float acc = b1[c];
    for(int k = 0; k < H; k++){
        acc += a[k]          * w1[(size_t)(2*H + k)*H + c];
        acc += tvec[b*H + k] * w1[(size_t)(3*H + k)*H + c];
    }
    ctab[(size_t)idx*RP + (c/3)*4 + (c%3)] = acc;
}

// ---------------- MFMA GEMM; obf: 0=fp32 row-H out, 2=fp8 padded-RP out ----------------
struct GemmP {
    const u16* wt[4];
    const float* bias[4];
    void* out[4];
    int obf[4];
};
__global__ __launch_bounds__(256) void k_gemm(const u16* __restrict__ A, GemmP P){
    int oi = blockIdx.y / 3, nt = blockIdx.y % 3;
    const u16* Wt = P.wt[oi];
    const float* bias = P.bias[oi];
    int wave = threadIdx.x >> 6, lane = threadIdx.x & 63;
    int quad = lane >> 4, l16 = lane & 15;
    int m0 = blockIdx.x*256 + wave*64;
    int n0 = nt*64;
    facc_t acc[4][4];
    #pragma unroll
    for(int i = 0; i < 4; i++)
        #pragma unroll
        for(int j = 0; j < 4; j++){ acc[i][j][0]=0.f; acc[i][j][1]=0.f; acc[i][j][2]=0.f; acc[i][j][3]=0.f; }
    #pragma unroll
    for(int kc = 0; kc < 6; kc++){
        int kb = kc*32 + quad*8;
        bfrag_t af[4], bg[4];
        #pragma unroll
        for(int i = 0; i < 4; i++) af[i] = *(const bfrag_t*)(A  + (size_t)(m0 + i*16 + l16)*H + kb);
        #pragma unroll
        for(int j = 0; j < 4; j++) bg[j] = *(const bfrag_t*)(Wt + (size_t)(n0 + j*16 + l16)*H + kb);
        #pragma unroll
        for(int i = 0; i < 4; i++)
            #pragma unroll
            for(int j = 0; j < 4; j++)
                acc[i][j] = __builtin_amdgcn_mfma_f32_16x16x32_bf16(af[i], bg[j], acc[i][j], 0, 0, 0);
    }
    float bv[4];
    #pragma unroll
    for(int j = 0; j < 4; j++) bv[j] = bias ? bias[n0 + j*16 + l16] : 0.f;
    if(P.obf[oi] == 2){
        u8* out = (u8*)P.out[oi];
        int byteoff[4];
        #pragma unroll
        for(int j = 0; j < 4; j++){
            int c = n0 + j*16 + l16;
            byteoff[j] = (c/3)*4 + (c%3);
        }
        #pragma unroll
        for(int i = 0; i < 4; i++){
            int rb = m0 + i*16 + quad*4;
            #pragma unroll
            for(int r = 0; r < 4; r++){
                int row = rb + r;
                if(row < NN){
                    #pragma unroll
                    for(int j = 0; j < 4; j++)
                        out[(size_t)row*RP + byteoff[j]] = (u8)enc8(acc[i][j][r] + bv[j]);
                }
            }
        }
    } else {
        float* out = (float*)P.out[oi];
        #pragma unroll
        for(int i = 0; i < 4; i++){
            int rb = m0 + i*16 + quad*4;
            #pragma unroll
            for(int r = 0; r < 4; r++){
                int row = rb + r;
                if(row < NN){
                    #pragma unroll
                    for(int j = 0; j < 4; j++)
                        out[(size_t)row*H + n0 + j*16 + l16] = acc[i][j][r] + bv[j];
                }
            }
        }
    }
}

// ---------------- fused attention + gate + LN; no-max softmax, 4-stream ----------------
__global__ __launch_bounds__(256) void k_attn(
    const float* __restrict__ Q, const u8* __restrict__ Kb,
    const u8* __restrict__ Vb, const float* __restrict__ XR,
    const float* __restrict__ etab, const int* __restrict__ ofs,
    const int* __restrict__ ssrc, const int* __restrict__ seix,
    const float* __restrict__ wb, const float* __restrict__ lng, const float* __restrict__ lnb,
    float* __restrict__ x, u16* __restrict__ xb)
{
    int n = blockIdx.x*4 + (threadIdx.x >> 6);
    int lane = threadIdx.x & 63;
    int ch = lane*3;
    size_t base = (size_t)n*H + ch;
    const float scale = 0.14433756729740646f;   // 1/sqrt(48)
    float q0 = Q[base], q1 = Q[base+1], q2 = Q[base+2];
    int p0 = ofs[n], p1 = ofs[n+1];
    float lac[4]  = {0.f,0.f,0.f,0.f};
    float ac0[4]  = {0.f,0.f,0.f,0.f};
    float ac1[4]  = {0.f,0.f,0.f,0.f};
    float ac2[4]  = {0.f,0.f,0.f,0.f};
    int p = p0;
    for(; p + 3 < p1; p += 4){
        int s[4], ei[4];
        #pragma unroll
        for(int t = 0; t < 4; t++){ s[t] = ssrc[p+t]; ei[t] = seix[p+t]; }
        u32 kw[4], vw[4];
        f4 ef[4];
        #pragma unroll
        for(int t = 0; t < 4; t++){
            kw[t] = *(const u32*)(Kb + (size_t)s[t]*RP + lane*4);
            ef[t] = *(const f4*)(etab + (size_t)ei[t]*RP + lane*4);
            vw[t] = *(const u32*)(Vb + (size_t)s[t]*RP + lane*4);
        }
        float tt[4];
        #pragma unroll
        for(int t = 0; t < 4; t++)
            tt[t] = q0*(dec8s<0>(kw[t])+ef[t].x) + q1*(dec8s<1>(kw[t])+ef[t].y)
                  + q2*(dec8s<2>(kw[t])+ef[t].z);
        #pragma unroll
        for(int o = 1; o <= 8; o <<= 1){
            #pragma unroll
            for(int t = 0; t < 4; t++) tt[t] += __shfl_xor(tt[t], o);
        }
        #pragma unroll
        for(int t = 0; t < 4; t++){
            float sc = fminf(fmaxf(tt[t]*scale, -60.f), 60.f);
            float pw = __expf(sc);
            lac[t] += pw;
            ac0[t] += pw*(dec8s<0>(vw[t])+ef[t].x);
            ac1[t] += pw*(dec8s<1>(vw[t])+ef[t].y);
            ac2[t] += pw*(dec8s<2>(vw[t])+ef[t].z);
        }
    }
    for(; p < p1; p++){
        int sA = ssrc[p], eiA = seix[p];
        u32 kwA = *(const u32*)(Kb + (size_t)sA*RP + lane*4);
        f4 efA = *(const f4*)(etab + (size_t)eiA*RP + lane*4);
        u32 vwA = *(const u32*)(Vb + (size_t)sA*RP + lane*4);
        float tA = q0*(dec8s<0>(kwA)+efA.x) + q1*(dec8s<1>(kwA)+efA.y) + q2*(dec8s<2>(kwA)+efA.z);
        tA += __shfl_xor(tA,1); tA += __shfl_xor(tA,2); tA += __shfl_xor(tA,4); tA += __shfl_xor(tA,8);
        float sc = fminf(fmaxf(tA*scale, -60.f), 60.f);
        float pw = __expf(sc);
        lac[0] += pw;
        ac0[0] += pw*(dec8s<0>(vwA)+efA.x);
        ac1[0] += pw*(dec8s<1>(vwA)+efA.y);
        ac2[0] += pw*(dec8s<2>(vwA)+efA.z);
    }
    float l  = (lac[0]+lac[1]) + (lac[2]+lac[3]);
    float a0 = (ac0[0]+ac0[1]) + (ac0[2]+ac0[3]);
    float a1 = (ac1[0]+ac1[1]) + (ac1[2]+ac1[3]);
    float a2 = (ac2[0]+ac2[1]) + (ac2[2]+ac2[3]);
    float inv = (p1 > p0) ? 1.f/l : 0.f;
    float o0 = a0*inv, o1 = a1*inv, o2 = a2*inv;
    float xr0 = XR[base], xr1 = XR[base+1], xr2 = XR[base+2];
    float sd = o0*wb[ch]  + o1*wb[ch+1]  + o2*wb[ch+2]
             + xr0*wb[H+ch] + xr1*wb[H+ch+1] + xr2*wb[H+ch+2]
             + (o0-xr0)*wb[2*H+ch] + (o1-xr1)*wb[2*H+ch+1] + (o2-xr2)*wb[2*H+ch+2];
    sd += __shfl_xor(sd,1); sd += __shfl_xor(sd,2); sd += __shfl_xor(sd,4);
    sd += __shfl_xor(sd,8); sd += __shfl_xor(sd,16); sd += __shfl_xor(sd,32);
    float beta = 1.f/(1.f + __expf(-sd));
    float h0 = beta*xr0 + (1.f-beta)*o0;
    float h1 = beta*xr1 + (1.f-beta)*o1;
    float h2 = beta*xr2 + (1.f-beta)*o2;
    float y0 = x[base] + h0, y1 = x[base+1] + h1, y2 = x[base+2] + h2;
    float s3 = y0 + y1 + y2;
    s3 += __shfl_xor(s3,1); s3 += __shfl_xor(s3,2); s3 += __shfl_xor(s3,4);
    s3 += __shfl_xor(s3,8); s3 += __shfl_xor(s3,16); s3 += __shfl_xor(s3,32);
    float mean = s3 * (1.f/H);
    float d0 = y0-mean, d1 = y1-mean, d2 = y2-mean;
    float v3 = d0*d0 + d1*d1 + d2*d2;
    v3 += __shfl_xor(v3,1); v3 += __shfl_xor(v3,2); v3 += __shfl_xor(v3,4);
    v3 += __shfl_xor(v3,8); v3 += __shfl_xor(v3,16); v3 += __shfl_xor(v3,32);
    float rs = rsqrtf(v3*(1.f/H) + 1e-5f);
    float z0 = d0*rs*lng[ch]   + lnb[ch];
    float z1 = d1*rs*lng[ch+1] + lnb[ch+1];
    float z2 = d2*rs*lng[ch+2] + lnb[ch+2];
    x[base] = z0; x[base+1] = z1; x[base+2] = z2;
    bf16 t0 = f2b(z0), t1 = f2b(z1), t2 = f2b(z2);
    xb[base] = *(u16*)&t0; xb[base+1] = *(u16*)&t1; xb[base+2] = *(u16*)&t2;
}

// ---------------- node logits ----------------
__global__ void k_nodeout(const float* __restrict__ x, const float* __restrict__ w,
                          const float* __restrict__ b, float* __restrict__ out){
    int j = threadIdx.x & 31;
    int n = blockIdx.x*8 + (threadIdx.x >> 5);
    float acc = b[j];
    const float* xr = x + (size_t)n*H;
    for(int k = 0; k < H; k++) acc += xr[k] * w[k*32 + j];
    out[(size_t)n*32 + j] = acc;
}

// ---------------- edge logits: dst-sorted traversal, 2-edge interleave, scatter writes ----------------
__global__ __launch_bounds__(256) void k_edgemlp(
    const int* __restrict__ ssrc, const int* __restrict__ sdst, const int* __restrict__ seix,
    const int* __restrict__ seorig,
    const u8* __restrict__ xs1, const u8* __restrict__ xd1, const float* __restrict__ ctab,
    const float* __restrict__ w2, const float* __restrict__ b2p, float* __restrict__ out)
{
    int wid = blockIdx.x*4 + (threadIdx.x >> 6);
    int lane = threadIdx.x & 63;
    int ch = lane*3;
    float w2r[3][8];
    #pragma unroll
    for(int t = 0; t < 3; t++)
        #pragma unroll
        for(int j = 0; j < 8; j++) w2r[t][j] = w2[(ch+t)*8 + j];
    int jout = (lane&1)*4 + (lane&2) + ((lane&4)>>2);
    float bo = (lane < 8) ? b2p[jout] : 0.f;
    int b0 = lane & 1, b1 = lane & 2, b2m = lane & 4;
    int e0 = wid*EML;
    for(int eb = e0; eb < e0 + EML; eb += 2){
        int sX = ssrc[eb],   dX = sdst[eb],   ctX = seix[eb],   oX = seorig[eb];
        int sY = ssrc[eb+1], dY = sdst[eb+1], ctY = seix[eb+1], oY = seorig[eb+1];
        u32 awX = *(const u32*)(xs1 + (size_t)sX*RP + lane*4);
        u32 awY = *(const u32*)(xs1 + (size_t)sY*RP + lane*4);
        u32 bwX = *(const u32*)(xd1 + (size_t)dX*RP + lane*4);
        u32 bwY = *(const u32*)(xd1 + (size_t)dY*RP + lane*4);
        f4  cfX = *(const f4*)(ctab + (size_t)ctX*RP + lane*4);
        f4  cfY = *(const f4*)(ctab + (size_t)ctY*RP + lane*4);
        float hX0, hX1, hX2, hY0, hY1, hY2;
        { float v = dec8s<0>(awX)+dec8s<0>(bwX)+cfX.x; hX0 = v*frcp(1.f+__expf(-v)); }
        { float v = dec8s<1>(awX)+dec8s<1>(bwX)+cfX.y; hX1 = v*frcp(1.f+__expf(-v)); }
        { float v = dec8s<2>(awX)+dec8s<2>(bwX)+cfX.z; hX2 = v*frcp(1.f+__expf(-v)); }
        { float v = dec8s<0>(awY)+dec8s<0>(bwY)+cfY.x; hY0 = v*frcp(1.f+__expf(-v)); }
        { float v = dec8s<1>(awY)+dec8s<1>(bwY)+cfY.y; hY1 = v*frcp(1.f+__expf(-v)); }
        { float v = dec8s<2>(awY)+dec8s<2>(bwY)+cfY.z; hY2 = v*frcp(1.f+__expf(-v)); }
        float pjX[8], pjY[8];
        #pragma unroll
        for(int j = 0; j < 8; j++){
            pjX[j] = hX0*w2r[0][j] + hX1*w2r[1][j] + hX2*w2r[2][j];
            pjY[j] = hY0*w2r[0][j] + hY1*w2r[1][j] + hY2*w2r[2][j];
        }
        float v4X[4], v4Y[4];
        #pragma unroll
        for(int t = 0; t < 4; t++){
            float sX4 = b0 ? pjX[t] : pjX[t+4];
            float kX4 = b0 ? pjX[t+4] : pjX[t];
            v4X[t] = kX4 + __shfl_xor(sX4, 1);
            float sY4 = b0 ? pjY[t] : pjY[t+4];
            float kY4 = b0 ? pjY[t+4] : pjY[t];
            v4Y[t] = kY4 + __shfl_xor(sY4, 1);
        }
        float v2X[2], v2Y[2];
        #pragma unroll
        for(int t = 0; t < 2; t++){
            float sX2 = b1 ? v4X[t] : v4X[t+2];
            float kX2 = b1 ? v4X[t+2] : v4X[t];
            v2X[t] = kX2 + __shfl_xor(sX2, 2);
            float sY2 = b1 ? v4Y[t] : v4Y[t+2];
            float kY2 = b1 ? v4Y[t+2] : v4Y[t];
            v2Y[t] = kY2 + __shfl_xor(sY2, 2);
        }
        float v1X, v1Y;
        {
            float sX1 = b2m ? v2X[0] : v2X[1];
            float kX1 = b2m ? v2X[1] : v2X[0];
            v1X = kX1 + __shfl_xor(sX1, 4);
            float sY1 = b2m ? v2Y[0] : v2Y[1];
            float kY1 = b2m ? v2Y[1] : v2Y[0];
            v1Y = kY1 + __shfl_xor(sY1, 4);
        }
        v1X += __shfl_xor(v1X, 8);  v1Y += __shfl_xor(v1Y, 8);
        v1X += __shfl_xor(v1X, 16); v1Y += __shfl_xor(v1Y, 16);
        v1X += __shfl_xor(v1X, 32); v1Y += __shfl_xor(v1Y, 32);
        if(lane < 8){
            out[(size_t)oX*8 + jout] = v1X + bo;
            out[(size_t)oY*8 + jout] = v1Y + bo;
        }
    }
}

extern "C" void kernel_launch(void* const* d_in, const int* in_sizes, int n_in,
                              void* d_out, int out_size, void* d_ws, size_t ws_size,
                              hipStream_t stream)
{
    {
        int bad = -1;
        if(n_in != 31) bad = 100;
        else {
            const int chk_idx[9] = {0, 7, 16, 21, 23, 26, 27, 29, 30};
            const int chk_sz [9] = {32*H, NL*HH, NL*3*H, 4*HH, H*8, NE, 2*NE, NN, NBATCH};
            for(int i = 0; i < 9; i++) if(in_sizes[chk_idx[i]] != chk_sz[i]){ bad = chk_idx[i]; break; }
        }
        if(bad >= 0){ k_sentinel<<<1,1,0,stream>>>((float*)d_out, 20000.f + 256.f*bad); return; }
        if(out_size != NN*32 + NE*8){ k_sentinel<<<1,1,0,stream>>>((float*)d_out, 30000.f); return; }
    }

    const float* node_emb = (const float*)d_in[0];
    const float* edge_emb = (const float*)d_in[1];
    const float* time_w1  = (const float*)d_in[2];
    const float* time_b1  = (const float*)d_in[3];
    const float* time_w2  = (const float*)d_in[4];
    const float* time_b2  = (const float*)d_in[5];
    const float* mask_emb = (const float*)d_in[6];
    const float* wq       = (const float*)d_in[7];
    const float* bq       = (const float*)d_in[8];
    const float* wk       = (const float*)d_in[9];
    const float* bk       = (const float*)d_in[10];
    const float* wv       = (const float*)d_in[11];
    const float* bv       = (const float*)d_in[12];
    const float* we       = (const float*)d_in[13];
    const float* wskip    = (const float*)d_in[14];
    const float* bskip    = (const float*)d_in[15];
    const float* wbeta    = (const float*)d_in[16];
    const float* ln_g     = (const float*)d_in[17];
    const float* ln_b     = (const float*)d_in[18];
    const float* now      = (const float*)d_in[19];
    const float* nob      = (const float*)d_in[20];
    const float* ew1      = (const float*)d_in[21];
    const float* eb1      = (const float*)d_in[22];
    const float* ew2      = (const float*)d_in[23];
    const float* eb2      = (const float*)d_in[24];
    const int* node_type  = (const int*)d_in[25];
    const int* edge_type  = (const int*)d_in[26];
    const int* edge_index = (const int*)d_in[27];
    const int* edit_mask  = (const int*)d_in[28];
    const int* node_batch = (const int*)d_in[29];
    const int* t_graph    = (const int*)d_in[30];
    const int* esrc = edge_index;
    const int* edst = edge_index + NE;

    char* wsb = (char*)d_ws;
    size_t off = 0;
    auto take = [&](size_t bytes) -> char* {
        char* r = wsb + off;
        off += (bytes + 255) & ~(size_t)255;
        return r;
    };
    float* tvec = (float*)take((size_t)NBATCH*H*4);
    float* x    = (float*)take((size_t)NN*H*4);
    u16*   xb   = (u16*)  take((size_t)NPAD*H*2);
    float* Q    = (float*)take((size_t)NN*H*4);
    u8*    Kb   = (u8*)   take((size_t)NN*RP);
    u8*    Vb   = (u8*)   take((size_t)NN*RP);
    float* XR   = (float*)take((size_t)NN*H*4);
    u8*    xs1  = (u8*)   take((size_t)NN*RP);
    u8*    xd1  = (u8*)   take((size_t)NN*RP);
    float* etab = (float*)take((size_t)NL*64*RP*4);
    float* ctab = (float*)take((size_t)64*RP*4);
    u16*   wt   = (u16*)  take((size_t)18*HH*2);
    int* cnt    = (int*)  take((size_t)(NN+1)*4);
    int* offa   = (int*)  take((size_t)(NN+1)*4);
    int* cur    = (int*)  take((size_t)(NN+1)*4);
    int* ssrc   = (int*)  take((size_t)NE*4);
    int* seix   = (int*)  take((size_t)NE*4);
    int* sdst   = (int*)  take((size_t)NE*4);
    int* seorig = (int*)  take((size_t)NE*4);

    if(ws_size < off){
        k_sentinel<<<1,1,0,stream>>>((float*)d_out, 10000.f + (float)(ws_size >> 20));
        return;
    }

    k_transpose<<<dim3(18, 8), 256, 0, stream>>>(wq, wk, wv, wskip, ew1, wt);
    k_tvec<<<NBATCH, H, 0, stream>>>(t_graph, time_w1, time_b1, time_w2, time_b2, tvec);
    k_init_x<<<(NN*H + 255)/256, 256, 0, stream>>>(node_emb, mask_emb, tvec, node_type,
                                                   edit_mask, node_batch, x, xb);
    k_zero_i<<<(NN + 255)/256, 256, 0, stream>>>(cnt, NN);
    k_count<<<NE/256, 256, 0, stream>>>(edst, cnt);
    k_scan<<<1, 1024, 0, stream>>>(cnt, offa, cur);
    k_scatter<<<NE/256, 256, 0, stream>>>(esrc, edst, edge_type, node_batch, cur,
                                          ssrc, seix, sdst, seorig);
    k_etab<<<NL*64, H, 0, stream>>>(edge_emb, tvec, we, etab);
    k_ctab<<<64, H, 0, stream>>>(edge_emb, tvec, ew1, eb1, ctab);

    for(int l = 0; l < NL; l++){
        GemmP P;
        P.wt[0] = wt + (size_t)(0  + l)*HH;  P.bias[0] = bq   + (size_t)l*H;  P.out[0] = Q;  P.obf[0] = 0;
        P.wt[1] = wt + (size_t)(4  + l)*HH;  P.bias[1] = bk   + (size_t)l*H;  P.out[1] = Kb; P.obf[1] = 2;
        P.wt[2] = wt + (size_t)(8  + l)*HH;  P.bias[2] = bv   + (size_t)l*H;  P.out[2] = Vb; P.obf[2] = 2;
        P.wt[3] = wt + (size_t)(12 + l)*HH;  P.bias[3] = bskip+ (size_t)l*H;  P.out[3] = XR; P.obf[3] = 0;
        k_gemm<<<dim3(63, 12), 256, 0, stream>>>(xb, P);
        k_attn<<<NN/4, 256, 0, stream>>>(Q, Kb, Vb, XR, etab + (size_t)l*64*RP, offa, ssrc, seix,
                                         wbeta + (size_t)l*3*H, ln_g + (size_t)l*H,
                                         ln_b + (size_t)l*H, x, xb);
    }
    {
        GemmP P;
        P.wt[0] = wt + (size_t)16*HH; P.bias[0] = nullptr; P.out[0] = xs1; P.obf[0] = 2;
        P.wt[1] = wt + (size_t)17*HH; P.bias[1] = nullptr; P.out[1] = xd1; P.obf[1] = 2;
        P.wt[2] = P.wt[0]; P.bias[2] = nullptr; P.out[2] = xs1; P.obf[2] = 2;
        P.wt[3] = P.wt[0]; P.bias[3] = nullptr; P.out[3] = xs1; P.obf[3] = 2;
        k_gemm<<<dim3(63, 6), 256, 0, stream>>>(xb, P);
    }
    k_nodeout<<<NN/8, 256, 0, stream>>>(x, now, nob, (float*)d_out);
    k_edgemlp<<<NE/(4*EML), 256, 0, stream>>>(ssrc, sdst, seix, seorig, xs1, xd1, ctab,
                                              ew2, eb2, (float*)d_out + (size_t)NN*32);
}